// Round 1
// baseline (1001.759 us; speedup 1.0000x reference)
//
#include <hip/hip_runtime.h>
#include <math.h>

#define NB 256      // B
#define NK 1024     // K
#define ND 2048     // D
#define NN 50000    // N
#define BM 64       // gemm rows per block

constexpr float T_INV = 1.0f / 0.07f;
constexpr float Z_INV = 1.0f / 52580.0f;
constexpr float MOM   = 0.5f;

typedef float f32x4 __attribute__((ext_vector_type(4)));
typedef short s16x8 __attribute__((ext_vector_type(8)));
typedef unsigned int u32x4 __attribute__((ext_vector_type(4)));

// ---------------------------------------------------------------- helpers
__device__ __forceinline__ float blk_reduce_sum256(float v, float* sh) {
    #pragma unroll
    for (int o = 32; o > 0; o >>= 1) v += __shfl_down(v, o, 64);
    int lane = threadIdx.x & 63;
    int wid  = threadIdx.x >> 6;
    if (lane == 0) sh[wid] = v;
    __syncthreads();
    float s = sh[0] + sh[1] + sh[2] + sh[3];
    __syncthreads();
    return s;
}

__device__ __forceinline__ unsigned f2bf_rne(float f) {
    unsigned u = __float_as_uint(f);
    return (u + 0x7fffu + ((u >> 16) & 1u)) >> 16;
}

// ------------------------------------------- 1) feat = x/||x||  (+ bf16 copy)
__global__ void k_feat(const float* __restrict__ x, float* __restrict__ feat,
                       unsigned int* __restrict__ featb) {   // featb: [NB][ND/2] packed bf16x2
    __shared__ float sh[4];
    int b = blockIdx.x;
    int t = threadIdx.x;
    const float4* xr = (const float4*)(x + (size_t)b * ND);
    float4 v0 = xr[t];
    float4 v1 = xr[t + 256];
    float ss = v0.x*v0.x + v0.y*v0.y + v0.z*v0.z + v0.w*v0.w
             + v1.x*v1.x + v1.y*v1.y + v1.z*v1.z + v1.w*v1.w;
    float s = blk_reduce_sum256(ss, sh);
    float r = rsqrtf(s);
    v0.x*=r; v0.y*=r; v0.z*=r; v0.w*=r;
    v1.x*=r; v1.y*=r; v1.z*=r; v1.w*=r;
    float4* fr = (float4*)(feat + (size_t)b * ND);
    fr[t]       = v0;
    fr[t + 256] = v1;
    unsigned int* fb = featb + (size_t)b * (ND / 2);
    fb[2*t]           = f2bf_rne(v0.x) | (f2bf_rne(v0.y) << 16);
    fb[2*t + 1]       = f2bf_rne(v0.z) | (f2bf_rne(v0.w) << 16);
    fb[2*(t+256)]     = f2bf_rne(v1.x) | (f2bf_rne(v1.y) << 16);
    fb[2*(t+256) + 1] = f2bf_rne(v1.z) | (f2bf_rne(v1.w) << 16);
}

// ------------- 2) S[n,b] = dot(mem[n], feat[b]) for ALL n,b  (+ fused temp copy)
// 256 thr = 4 waves. Block: BM=64 rows x all 256 cols. Wave w: cols [w*64, w*64+64).
// MFMA 16x16x32 bf16. A frag: lane holds mem[row0+(l&15)][k0+(l>>4)*8 ..+8] (fp32->bf16 trunc).
// B frag: lane holds featb[c0+(l&15)][k0+(l>>4)*8 ..+8].
// D frag (m89-verified): col = lane&15, row = (lane>>4)*4 + reg.
template<bool COPY>
__launch_bounds__(256)
__global__ void k_gemm(const float* __restrict__ mem, const short* __restrict__ featb,
                       float* __restrict__ S, float* __restrict__ temp) {
    const int wave = threadIdx.x >> 6;
    const int lane = threadIdx.x & 63;
    const int rlo  = lane & 15;
    const int khi  = lane >> 4;           // 0..3 -> k offset khi*8
    const int n0   = blockIdx.x * BM;

    const float* aptr[4];
    #pragma unroll
    for (int m = 0; m < 4; ++m) {
        int r = n0 + m * 16 + rlo;
        if (r >= NN) r = NN - 1;          // clamp; results for OOB rows never stored
        aptr[m] = mem + (size_t)r * ND + khi * 8;
    }
    const short* bptr[4];
    #pragma unroll
    for (int j = 0; j < 4; ++j) {
        int c = wave * 64 + j * 16 + rlo;
        bptr[j] = featb + (size_t)c * ND + khi * 8;
    }
    // fused-copy lane assignment: 4 threads per row, 8 floats each per K-step
    const int crow = n0 + (threadIdx.x >> 2);
    const int ccol = (threadIdx.x & 3) * 8;
    const bool cok = COPY && (crow < NN);
    const float4* csrc = (const float4*)(mem  + (size_t)crow * ND + ccol);
    float4*       cdst = (float4*)(temp + (size_t)crow * ND + ccol);

    f32x4 acc[4][4] = {};

    for (int k0 = 0; k0 < ND; k0 += 32) {
        s16x8 bfr[4];
        #pragma unroll
        for (int j = 0; j < 4; ++j)
            bfr[j] = *(const s16x8*)(bptr[j] + k0);
        s16x8 afr[4];
        #pragma unroll
        for (int m = 0; m < 4; ++m) {
            const float* p = aptr[m] + k0;
            float4 x0 = *(const float4*)p;
            float4 x1 = *(const float4*)(p + 4);
            u32x4 uv = { (__float_as_uint(x0.x) >> 16) | (__float_as_uint(x0.y) & 0xffff0000u),
                         (__float_as_uint(x0.z) >> 16) | (__float_as_uint(x0.w) & 0xffff0000u),
                         (__float_as_uint(x1.x) >> 16) | (__float_as_uint(x1.y) & 0xffff0000u),
                         (__float_as_uint(x1.z) >> 16) | (__float_as_uint(x1.w) & 0xffff0000u) };
            afr[m] = __builtin_bit_cast(s16x8, uv);
        }
        #pragma unroll
        for (int m = 0; m < 4; ++m)
            #pragma unroll
            for (int j = 0; j < 4; ++j)
                acc[m][j] = __builtin_amdgcn_mfma_f32_16x16x32_bf16(afr[m], bfr[j], acc[m][j], 0, 0, 0);
        if (cok) {  // coalesced L2-hot re-read of this K-slab, streamed to temp
            cdst[k0 / 4]     = csrc[k0 / 4];
            cdst[k0 / 4 + 1] = csrc[k0 / 4 + 1];
        }
    }

    const int r_off = (lane >> 4) * 4;
    const int c_off = lane & 15;
    #pragma unroll
    for (int m = 0; m < 4; ++m) {
        int row0 = n0 + m * 16 + r_off;
        #pragma unroll
        for (int j = 0; j < 4; ++j) {
            int col = wave * 64 + j * 16 + c_off;
            #pragma unroll
            for (int r = 0; r < 4; ++r) {
                int row = row0 + r;
                if (row < NN) S[(size_t)row * NB + col] = acc[m][j][r];
            }
        }
    }
}

// --------------------------- 3) out[b,k] = exp(S[row,b]/T)/Z, row = (k==0? y : idx)
__global__ void k_out(const float* __restrict__ S, const int* __restrict__ idx,
                      const int* __restrict__ y, float* __restrict__ out) {
    int g = blockIdx.x * 256 + threadIdx.x;      // 0 .. NB*NK
    int b = g >> 10;
    int k = g & (NK - 1);
    int row = (k == 0) ? y[b] : idx[g];
    out[g] = expf(S[(size_t)row * NB + b] * T_INV) * Z_INV;
}

// ------------------------------------------------- fallback full copy
__global__ void k_copy(const float* __restrict__ mem, float* __restrict__ temp) {
    size_t i = (size_t)blockIdx.x * 256 + threadIdx.x;
    ((float4*)temp)[i] = ((const float4*)mem)[i];
}

// ---------------------- 4) temp[y[b]] = normalize(MOM*mem[y[b]] + (1-MOM)*feat[b])
__global__ void k_scatter(const float* __restrict__ mem, const float* __restrict__ feat,
                          const int* __restrict__ y, float* __restrict__ temp) {
    __shared__ float sh[4];
    int b  = blockIdx.x;
    int yb = y[b];
    for (int b2 = b + 1; b2 < NB; ++b2)
        if (y[b2] == yb) return;                 // last-write-wins, uniform branch
    int t = threadIdx.x;
    const float4* f4 = (const float4*)(feat + (size_t)b * ND);
    const float4* m4 = (const float4*)(mem  + (size_t)yb * ND);
    float4 f0 = f4[t], f1 = f4[t + 256];
    float4 m0 = m4[t], m1 = m4[t + 256];
    float4 w0 = make_float4(m0.x*MOM + f0.x*(1.f-MOM), m0.y*MOM + f0.y*(1.f-MOM),
                            m0.z*MOM + f0.z*(1.f-MOM), m0.w*MOM + f0.w*(1.f-MOM));
    float4 w1 = make_float4(m1.x*MOM + f1.x*(1.f-MOM), m1.y*MOM + f1.y*(1.f-MOM),
                            m1.z*MOM + f1.z*(1.f-MOM), m1.w*MOM + f1.w*(1.f-MOM));
    float ss = w0.x*w0.x + w0.y*w0.y + w0.z*w0.z + w0.w*w0.w
             + w1.x*w1.x + w1.y*w1.y + w1.z*w1.z + w1.w*w1.w;
    float s = blk_reduce_sum256(ss, sh);
    float r = rsqrtf(s);
    float4* d = (float4*)(temp + (size_t)yb * ND);
    d[t]       = make_float4(w0.x*r, w0.y*r, w0.z*r, w0.w*r);
    d[t + 256] = make_float4(w1.x*r, w1.y*r, w1.z*r, w1.w*r);
}

// ---------------------------------------------------------------- launch
extern "C" void kernel_launch(void* const* d_in, const int* in_sizes, int n_in,
                              void* d_out, int out_size, void* d_ws, size_t ws_size,
                              hipStream_t stream) {
    (void)in_sizes; (void)n_in; (void)out_size;
    const float* x   = (const float*)d_in[0];
    const int*   y   = (const int*)d_in[1];
    const int*   idx = (const int*)d_in[2];
    const float* mem = (const float*)d_in[3];

    float* out  = (float*)d_out;                       // [B*K]
    float* temp = (float*)d_out + (size_t)NB * NK;     // [N*D]

    const size_t szF  = (size_t)NB * ND * sizeof(float);    // 2 MB  feat fp32
    const size_t szFB = (size_t)NB * ND * sizeof(short);    // 1 MB  feat bf16
    const size_t szS  = (size_t)NN * NB * sizeof(float);    // 51.2 MB scores
    const int gemm_grid = (NN + BM - 1) / BM;               // 782

    if (ws_size >= szF + szFB + szS) {
        // main path: S in workspace, temp copy fused into the GEMM
        float*        feat  = (float*)d_ws;
        unsigned int* featb = (unsigned int*)((char*)d_ws + szF);
        float*        S     = (float*)((char*)d_ws + szF + szFB);
        k_feat<<<NB, 256, 0, stream>>>(x, feat, featb);
        k_gemm<true><<<gemm_grid, 256, 0, stream>>>(mem, (const short*)featb, S, temp);
        k_out<<<(NB * NK) / 256, 256, 0, stream>>>(S, idx, y, out);
        k_scatter<<<NB, 256, 0, stream>>>(mem, feat, y, temp);
    } else {
        // fallback: stage featb + S in the temp region (overwritten by k_copy afterward)
        float*        feat  = (float*)d_ws;                      // prior session proved >=2MB
        unsigned int* featb = (unsigned int*)temp;
        float*        S     = (float*)((char*)temp + szFB);
        k_feat<<<NB, 256, 0, stream>>>(x, feat, featb);
        k_gemm<false><<<gemm_grid, 256, 0, stream>>>(mem, (const short*)featb, S, nullptr);
        k_out<<<(NB * NK) / 256, 256, 0, stream>>>(S, idx, y, out);
        k_copy<<<(NN * ND / 4) / 256, 256, 0, stream>>>(mem, temp);
        k_scatter<<<NB, 256, 0, stream>>>(mem, feat, y, temp);
    }
}

// Round 2
// 812.941 us; speedup vs baseline: 1.2323x; 1.2323x over previous
//
#include <hip/hip_runtime.h>
#include <math.h>

#define NB 256      // B
#define NK 1024     // K
#define ND 2048     // D
#define NN 50000    // N
#define BM 32       // gemm rows per block
#define NT (ND / 64) // 32 K-tiles of 64 floats

constexpr float T_INV = 1.0f / 0.07f;
constexpr float Z_INV = 1.0f / 52580.0f;
constexpr float MOM   = 0.5f;

typedef float f32x4 __attribute__((ext_vector_type(4)));
typedef short s16x8 __attribute__((ext_vector_type(8)));
typedef unsigned int u32x4 __attribute__((ext_vector_type(4)));

#define AS1 __attribute__((address_space(1)))
#define AS3 __attribute__((address_space(3)))
#define SB() __builtin_amdgcn_sched_barrier(0)

// ---------------------------------------------------------------- helpers
__device__ __forceinline__ float blk_reduce_sum256(float v, float* sh) {
    #pragma unroll
    for (int o = 32; o > 0; o >>= 1) v += __shfl_down(v, o, 64);
    int lane = threadIdx.x & 63;
    int wid  = threadIdx.x >> 6;
    if (lane == 0) sh[wid] = v;
    __syncthreads();
    float s = sh[0] + sh[1] + sh[2] + sh[3];
    __syncthreads();
    return s;
}

__device__ __forceinline__ unsigned f2bf_rne(float f) {
    unsigned u = __float_as_uint(f);
    return (u + 0x7fffu + ((u >> 16) & 1u)) >> 16;
}

// truncating fp32->bf16 pack of 8 floats (matches prior passing numerics)
__device__ __forceinline__ s16x8 pack_bf16(f32x4 a, f32x4 b) {
    u32x4 uv = { (__float_as_uint(a[0]) >> 16) | (__float_as_uint(a[1]) & 0xffff0000u),
                 (__float_as_uint(a[2]) >> 16) | (__float_as_uint(a[3]) & 0xffff0000u),
                 (__float_as_uint(b[0]) >> 16) | (__float_as_uint(b[1]) & 0xffff0000u),
                 (__float_as_uint(b[2]) >> 16) | (__float_as_uint(b[3]) & 0xffff0000u) };
    return __builtin_bit_cast(s16x8, uv);
}

// ------------------------------------------- 1) feat = x/||x||  (+ bf16 copy)
__global__ void k_feat(const float* __restrict__ x, float* __restrict__ feat,
                       unsigned int* __restrict__ featb) {   // featb: [NB][ND/2] bf16x2
    __shared__ float sh[4];
    int b = blockIdx.x;
    int t = threadIdx.x;
    const float4* xr = (const float4*)(x + (size_t)b * ND);
    float4 v0 = xr[t];
    float4 v1 = xr[t + 256];
    float ss = v0.x*v0.x + v0.y*v0.y + v0.z*v0.z + v0.w*v0.w
             + v1.x*v1.x + v1.y*v1.y + v1.z*v1.z + v1.w*v1.w;
    float s = blk_reduce_sum256(ss, sh);
    float r = rsqrtf(s);
    v0.x*=r; v0.y*=r; v0.z*=r; v0.w*=r;
    v1.x*=r; v1.y*=r; v1.z*=r; v1.w*=r;
    float4* fr = (float4*)(feat + (size_t)b * ND);
    fr[t]       = v0;
    fr[t + 256] = v1;
    unsigned int* fb = featb + (size_t)b * (ND / 2);
    fb[2*t]           = f2bf_rne(v0.x) | (f2bf_rne(v0.y) << 16);
    fb[2*t + 1]       = f2bf_rne(v0.z) | (f2bf_rne(v0.w) << 16);
    fb[2*(t+256)]     = f2bf_rne(v1.x) | (f2bf_rne(v1.y) << 16);
    fb[2*(t+256) + 1] = f2bf_rne(v1.z) | (f2bf_rne(v1.w) << 16);
}

// ------------- 2) S[n,b] = dot(mem[n], feat[b])  (+ fused temp copy from LDS)
// BM=32 rows x all 256 cols per block, 4 waves (each 32x64), MFMA 16x16x32 bf16.
// A staged fp32 -> LDS via global_load_lds (double-buffered, XOR-swizzled source),
// counted vmcnt + raw s_barrier (T3/T4); B frags in regs, loaded one tile ahead.
template<bool COPY>
__launch_bounds__(256)
__global__ void k_gemm(const float* __restrict__ mem, const short* __restrict__ featb,
                       float* __restrict__ S, float* __restrict__ temp) {
    __shared__ __align__(16) float As[2 * 2048];   // 2 bufs x 32 rows x 64 floats
    const int tid  = threadIdx.x;
    const int wave = tid >> 6;
    const int lane = tid & 63;
    const int rlo  = lane & 15;
    const int khi  = lane >> 4;
    const int n0   = blockIdx.x * BM;

    // gll per-lane global sources (rounds r=0: rows 0..15, r=1: rows 16..31).
    // Dest is linear (chunk g = tid), so source chunk is pre-swizzled: cc ^ (row&15).
    const int grow = tid >> 4;          // 0..15
    const int gcc  = tid & 15;
    const float* gsrc0;
    const float* gsrc1;
    {
        int r0 = grow,      a0 = n0 + r0; if (a0 >= NN) a0 = NN - 1;
        int r1 = 16 + grow, a1 = n0 + r1; if (a1 >= NN) a1 = NN - 1;
        gsrc0 = mem + (size_t)a0 * ND + ((gcc ^ grow) * 4);   // r0&15 == grow
        gsrc1 = mem + (size_t)a1 * ND + ((gcc ^ grow) * 4);   // r1&15 == grow
    }

    // B fragment pointers (featb row-major [col][k], bf16)
    const short* bp0 = featb + (size_t)(wave * 64 +  0 + rlo) * ND + khi * 8;
    const short* bp1 = featb + (size_t)(wave * 64 + 16 + rlo) * ND + khi * 8;
    const short* bp2 = featb + (size_t)(wave * 64 + 32 + rlo) * ND + khi * 8;
    const short* bp3 = featb + (size_t)(wave * 64 + 48 + rlo) * ND + khi * 8;

    // copy-out destinations (from LDS -> temp), same row/chunk split as gll
    float* cd0 = nullptr; float* cd1 = nullptr; bool cok0 = false, cok1 = false;
    if (COPY) {
        int c0 = n0 + grow;      cok0 = c0 < NN; cd0 = temp + (size_t)c0 * ND + gcc * 4;
        int c1 = n0 + 16 + grow; cok1 = c1 < NN; cd1 = temp + (size_t)c1 * ND + gcc * 4;
    }

    // LDS float-index bases
    const int a0base = rlo * 64;           // frag row m=0
    const int a1base = (16 + rlo) * 64;    // frag row m=1
    const int cl0 = grow * 64        + ((gcc ^ grow) * 4);   // copy row r=0
    const int cl1 = (16 + grow) * 64 + ((gcc ^ grow) * 4);   // copy row r=1

    f32x4 acc[2][4] = {};
    s16x8 bfr[8];   // [s*4+j], single set, loaded one tile ahead

    auto GLL = [&](int buf, int kf) {
        __builtin_amdgcn_global_load_lds((const AS1 void*)(gsrc0 + kf),
            (AS3 void*)(As + buf * 2048 + tid * 4), 16, 0, 0);
        __builtin_amdgcn_global_load_lds((const AS1 void*)(gsrc1 + kf),
            (AS3 void*)(As + buf * 2048 + 1024 + tid * 4), 16, 0, 0);
    };
    auto BLOAD = [&](int kf) {
        #pragma unroll
        for (int s = 0; s < 2; ++s) {
            bfr[s*4+0] = *(const s16x8*)(bp0 + kf + s*32);
            bfr[s*4+1] = *(const s16x8*)(bp1 + kf + s*32);
            bfr[s*4+2] = *(const s16x8*)(bp2 + kf + s*32);
            bfr[s*4+3] = *(const s16x8*)(bp3 + kf + s*32);
        }
    };
    auto COMPUTE = [&](int kf, int buf, bool pre) {
        const float* ab = As + buf * 2048;
        #pragma unroll
        for (int s = 0; s < 2; ++s) {
            const int ch = s * 8 + khi * 2;
            f32x4 a00 = *(const f32x4*)(ab + a0base + (((ch + 0) ^ rlo) * 4));
            f32x4 a01 = *(const f32x4*)(ab + a0base + (((ch + 1) ^ rlo) * 4));
            f32x4 a10 = *(const f32x4*)(ab + a1base + (((ch + 0) ^ rlo) * 4));
            f32x4 a11 = *(const f32x4*)(ab + a1base + (((ch + 1) ^ rlo) * 4));
            s16x8 af0 = pack_bf16(a00, a01);
            s16x8 af1 = pack_bf16(a10, a11);
            #pragma unroll
            for (int j = 0; j < 4; ++j) {
                acc[0][j] = __builtin_amdgcn_mfma_f32_16x16x32_bf16(af0, bfr[s*4+j], acc[0][j], 0, 0, 0);
                acc[1][j] = __builtin_amdgcn_mfma_f32_16x16x32_bf16(af1, bfr[s*4+j], acc[1][j], 0, 0, 0);
            }
        }
        if (pre) BLOAD(kf + 64);           // next tile's B, hidden under copy+barriers
        if (COPY) {                        // temp copy served from LDS (mem read once)
            f32x4 v0 = *(const f32x4*)(ab + cl0);
            f32x4 v1 = *(const f32x4*)(ab + cl1);
            if (cok0) *(f32x4*)(cd0 + kf) = v0;
            if (cok1) *(f32x4*)(cd1 + kf) = v1;
        }
    };

    // ---- prologue: tile 0 (full drain once)
    GLL(0, 0);
    BLOAD(0);
    asm volatile("s_waitcnt vmcnt(0)" ::: "memory");
    SB();
    __builtin_amdgcn_s_barrier();
    SB();
    // ---- t = 0 (buf0 ready; prefetch tile1)
    GLL(1, 64);
    COMPUTE(0, 0, true);
    // ---- main loop t = 1 .. NT-2
    for (int t = 1; t < NT - 1; ++t) {
        const int cur = t & 1;
        SB();
        __builtin_amdgcn_s_barrier();      // all waves done reading buf(cur^1)
        SB();
        GLL(cur ^ 1, (t + 1) * 64);        // prefetch tile t+1
        // ensure own gll(t) landed: newer ops = B(t)8 [+st(t-1)2 if COPY] + gll(t+1)2
        asm volatile("s_waitcnt vmcnt(%0)" :: "n"(COPY ? 12 : 10) : "memory");
        SB();
        __builtin_amdgcn_s_barrier();      // all waves' gll(t) landed
        SB();
        COMPUTE(t * 64, cur, true);
    }
    // ---- epilogue t = NT-1 (odd -> buf1), no prefetch
    SB();
    __builtin_amdgcn_s_barrier();
    SB();
    asm volatile("s_waitcnt vmcnt(%0)" :: "n"(COPY ? 10 : 8) : "memory");
    SB();
    __builtin_amdgcn_s_barrier();
    SB();
    COMPUTE((NT - 1) * 64, 1, false);

    // ---- C-write: col = wave*64 + j*16 + (lane&15), row = n0 + m*16 + (lane>>4)*4 + r
    const int r_off = khi * 4;
    #pragma unroll
    for (int m = 0; m < 2; ++m) {
        int row0 = n0 + m * 16 + r_off;
        #pragma unroll
        for (int j = 0; j < 4; ++j) {
            int col = wave * 64 + j * 16 + rlo;
            #pragma unroll
            for (int r = 0; r < 4; ++r) {
                int row = row0 + r;
                if (row < NN) S[(size_t)row * NB + col] = acc[m][j][r];
            }
        }
    }
}

// --------------------------- 3) out[b,k] = exp(S[row,b]/T)/Z, row = (k==0? y : idx)
__global__ void k_out(const float* __restrict__ S, const int* __restrict__ idx,
                      const int* __restrict__ y, float* __restrict__ out) {
    int g = blockIdx.x * 256 + threadIdx.x;
    int b = g >> 10;
    int k = g & (NK - 1);
    int row = (k == 0) ? y[b] : idx[g];
    out[g] = expf(S[(size_t)row * NB + b] * T_INV) * Z_INV;
}

// ------------------------------------------------- fallback full copy
__global__ void k_copy(const float* __restrict__ mem, float* __restrict__ temp) {
    size_t i = (size_t)blockIdx.x * 256 + threadIdx.x;
    ((float4*)temp)[i] = ((const float4*)mem)[i];
}

// ---------------------- 4) temp[y[b]] = normalize(MOM*mem[y[b]] + (1-MOM)*feat[b])
__global__ void k_scatter(const float* __restrict__ mem, const float* __restrict__ feat,
                          const int* __restrict__ y, float* __restrict__ temp) {
    __shared__ float sh[4];
    int b  = blockIdx.x;
    int yb = y[b];
    for (int b2 = b + 1; b2 < NB; ++b2)
        if (y[b2] == yb) return;                 // last-write-wins, uniform branch
    int t = threadIdx.x;
    const float4* f4 = (const float4*)(feat + (size_t)b * ND);
    const float4* m4 = (const float4*)(mem  + (size_t)yb * ND);
    float4 f0 = f4[t], f1 = f4[t + 256];
    float4 m0 = m4[t], m1 = m4[t + 256];
    float4 w0 = make_float4(m0.x*MOM + f0.x*(1.f-MOM), m0.y*MOM + f0.y*(1.f-MOM),
                            m0.z*MOM + f0.z*(1.f-MOM), m0.w*MOM + f0.w*(1.f-MOM));
    float4 w1 = make_float4(m1.x*MOM + f1.x*(1.f-MOM), m1.y*MOM + f1.y*(1.f-MOM),
                            m1.z*MOM + f1.z*(1.f-MOM), m1.w*MOM + f1.w*(1.f-MOM));
    float ss = w0.x*w0.x + w0.y*w0.y + w0.z*w0.z + w0.w*w0.w
             + w1.x*w1.x + w1.y*w1.y + w1.z*w1.z + w1.w*w1.w;
    float s = blk_reduce_sum256(ss, sh);
    float r = rsqrtf(s);
    float4* d = (float4*)(temp + (size_t)yb * ND);
    d[t]       = make_float4(w0.x*r, w0.y*r, w0.z*r, w0.w*r);
    d[t + 256] = make_float4(w1.x*r, w1.y*r, w1.z*r, w1.w*r);
}

// ---------------------------------------------------------------- launch
extern "C" void kernel_launch(void* const* d_in, const int* in_sizes, int n_in,
                              void* d_out, int out_size, void* d_ws, size_t ws_size,
                              hipStream_t stream) {
    (void)in_sizes; (void)n_in; (void)out_size;
    const float* x   = (const float*)d_in[0];
    const int*   y   = (const int*)d_in[1];
    const int*   idx = (const int*)d_in[2];
    const float* mem = (const float*)d_in[3];

    float* out  = (float*)d_out;                       // [B*K]
    float* temp = (float*)d_out + (size_t)NB * NK;     // [N*D]

    const size_t szF  = (size_t)NB * ND * sizeof(float);    // 2 MB  feat fp32
    const size_t szFB = (size_t)NB * ND * sizeof(short);    // 1 MB  feat bf16
    const size_t szS  = (size_t)NN * NB * sizeof(float);    // 51.2 MB scores
    const int gemm_grid = (NN + BM - 1) / BM;               // 1563

    if (ws_size >= szF + szFB + szS) {
        float*        feat  = (float*)d_ws;
        unsigned int* featb = (unsigned int*)((char*)d_ws + szF);
        float*        Smat  = (float*)((char*)d_ws + szF + szFB);
        k_feat<<<NB, 256, 0, stream>>>(x, feat, featb);
        k_gemm<true><<<gemm_grid, 256, 0, stream>>>(mem, (const short*)featb, Smat, temp);
        k_out<<<(NB * NK) / 256, 256, 0, stream>>>(Smat, idx, y, out);
        k_scatter<<<NB, 256, 0, stream>>>(mem, feat, y, temp);
    } else {
        float*        feat  = (float*)d_ws;
        unsigned int* featb = (unsigned int*)temp;
        float*        Smat  = (float*)((char*)temp + szFB);
        k_feat<<<NB, 256, 0, stream>>>(x, feat, featb);
        k_gemm<false><<<gemm_grid, 256, 0, stream>>>(mem, (const short*)featb, Smat, nullptr);
        k_out<<<(NB * NK) / 256, 256, 0, stream>>>(Smat, idx, y, out);
        k_copy<<<(NN * ND / 4) / 256, 256, 0, stream>>>(mem, temp);
        k_scatter<<<NB, 256, 0, stream>>>(mem, feat, y, temp);
    }
}